// Round 7
// baseline (3782.534 us; speedup 1.0000x reference)
//
#include <hip/hip_runtime.h>
#include <math.h>

#define HB 8
#define TT 1024
#define NSTATE 16
#define NTT 6
#define NMM 8
#define MM (HB*TT)   /* 8192 rows */
#define EPSV 1e-5f
#define CHUNK 64
#define NCH (TT/CHUNK)   /* 16 */
#define LSTR 72          /* GEMM LDS row stride in halves: [32 hi|32 lo|8 pad] */
#define AKS 128          /* attention keys staged per block iter */
#define VSTR 132         /* V-transpose LDS stride (halves) */

typedef _Float16 f16x8 __attribute__((ext_vector_type(8)));
typedef _Float16 f16x4 __attribute__((ext_vector_type(4)));
typedef float f32x4_t __attribute__((ext_vector_type(4)));

static __device__ inline void split8(const float4 a, const float4 b,
                                     f16x8& h, f16x8& l)
{
  float x[8] = {a.x, a.y, a.z, a.w, b.x, b.y, b.z, b.w};
#pragma unroll
  for (int i = 0; i < 8; i++) {
    _Float16 hi = (_Float16)x[i];
    h[i] = hi;
    l[i] = (_Float16)(x[i] - (float)hi);
  }
}

// ---------------------------------------------------------------------------
// fp32 -> (hi, lo) f16 planes. 4 elements/thread.
// ---------------------------------------------------------------------------
__global__ __launch_bounds__(256) void split_k(
    const float* __restrict__ X, _Float16* __restrict__ Hi,
    _Float16* __restrict__ Lo)
{
  const size_t i = ((size_t)blockIdx.x * 256 + threadIdx.x) * 4;
  float4 v = *(const float4*)&X[i];
  float x[4] = {v.x, v.y, v.z, v.w};
  f16x4 h, l;
#pragma unroll
  for (int j = 0; j < 4; j++) {
    _Float16 hi = (_Float16)x[j];
    h[j] = hi;
    l[j] = (_Float16)(x[j] - (float)hi);
  }
  *(f16x4*)&Hi[i] = h;
  *(f16x4*)&Lo[i] = l;
}

// ---------------------------------------------------------------------------
// fp16x3 split-precision MFMA GEMM, tile 128xTN, BK=32, optional split-K.
// If Ahi/Whi are non-null they are pre-split f16 planes (stride lda / K) and
// staging is pure copy; else inline fp32->hi/lo split.
// ---------------------------------------------------------------------------
template<int TN>
__global__ __launch_bounds__(256) void gemm_mfma_t(
    const float* __restrict__ A, int lda,
    const float* __restrict__ W,
    const _Float16* __restrict__ Ahi, const _Float16* __restrict__ Alo,
    const _Float16* __restrict__ Whi, const _Float16* __restrict__ Wlo,
    const float* __restrict__ bias,
    float* __restrict__ C,
    float* __restrict__ P,
    int N, int K, int S, int act)
{
  __shared__ _Float16 As[128 * LSTR];
  __shared__ _Float16 Bs[TN * LSTR];
  const int tid = threadIdx.x;
  const int m0 = blockIdx.y * 128;
  const int n0 = blockIdx.x * TN;
  const int z = blockIdx.z;
  const int kchunk = K / S;
  const int kb = z * kchunk;
  const int ke = kb + kchunk;

  const int lr = tid >> 1;
  const int lh = tid & 1;
  const int lane = tid & 63;
  const int w = tid >> 6;
  const int quad = lane >> 4;
  const int l16 = lane & 15;

  const float* Arow = A + (size_t)(m0 + lr) * lda + lh * 16;
  const _Float16* AHrow = Ahi ? (Ahi + (size_t)(m0 + lr) * lda + lh * 16) : nullptr;
  const _Float16* ALrow = Ahi ? (Alo + (size_t)(m0 + lr) * lda + lh * 16) : nullptr;
  _Float16* Adst = &As[lr * LSTR + lh * 16];

  constexpr int MI = (TN == 128) ? 4 : 2;
  const int w0 = (TN == 128) ? (w & 1) : w;
  const int w1 = (TN == 128) ? (w >> 1) : 0;
  const int rowbase = (TN == 128) ? w0 * 64 : w0 * 32;

  f32x4_t acc[MI][4];
#pragma unroll
  for (int i = 0; i < MI; i++)
#pragma unroll
    for (int j = 0; j < 4; j++)
#pragma unroll
      for (int r = 0; r < 4; r++) acc[i][j][r] = 0.f;

  const _Float16* ab = &As[(rowbase + l16) * LSTR + quad * 8];
  const _Float16* bb = &Bs[(w1 * 64 + l16) * LSTR + quad * 8];

  const float* Wrow;
  const _Float16* WHrow = nullptr;
  const _Float16* WLrow = nullptr;
  _Float16* Bdst;
  if (TN == 128) {
    Wrow = W + (size_t)(n0 + lr) * K + lh * 16;
    if (Whi) {
      WHrow = Whi + (size_t)(n0 + lr) * K + lh * 16;
      WLrow = Wlo + (size_t)(n0 + lr) * K + lh * 16;
    }
    Bdst = &Bs[lr * LSTR + lh * 16];
  } else {
    const int br = tid >> 2;
    const int bo = (tid & 3) * 8;
    Wrow = W + (size_t)(n0 + br) * K + bo;
    if (Whi) {
      WHrow = Whi + (size_t)(n0 + br) * K + bo;
      WLrow = Wlo + (size_t)(n0 + br) * K + bo;
    }
    Bdst = &Bs[br * LSTR + bo];
  }

  for (int k0 = kb; k0 < ke; k0 += 32) {
    // ---- global loads into registers
    f16x8 ah0, ah1, al0, al1;
    float4 a0, a1, a2, a3;
    if (Ahi) {
      ah0 = *(const f16x8*)&AHrow[k0];
      ah1 = *(const f16x8*)&AHrow[k0 + 8];
      al0 = *(const f16x8*)&ALrow[k0];
      al1 = *(const f16x8*)&ALrow[k0 + 8];
    } else {
      a0 = *(const float4*)&Arow[k0];
      a1 = *(const float4*)&Arow[k0 + 4];
      a2 = *(const float4*)&Arow[k0 + 8];
      a3 = *(const float4*)&Arow[k0 + 12];
    }
    f16x8 wh0, wh1, wl0, wl1;
    float4 b0, b1, b2, b3;
    if (Whi) {
      wh0 = *(const f16x8*)&WHrow[k0];
      wl0 = *(const f16x8*)&WLrow[k0];
      if (TN == 128) {
        wh1 = *(const f16x8*)&WHrow[k0 + 8];
        wl1 = *(const f16x8*)&WLrow[k0 + 8];
      }
    } else {
      b0 = *(const float4*)&Wrow[k0];
      b1 = *(const float4*)&Wrow[k0 + 4];
      if (TN == 128) {
        b2 = *(const float4*)&Wrow[k0 + 8];
        b3 = *(const float4*)&Wrow[k0 + 12];
      }
    }
    __syncthreads();
    // ---- LDS staging
    if (Ahi) {
      *(f16x8*)&Adst[0] = ah0; *(f16x8*)&Adst[8] = ah1;
      *(f16x8*)&Adst[32] = al0; *(f16x8*)&Adst[40] = al1;
    } else {
      f16x8 h, l;
      split8(a0, a1, h, l);
      *(f16x8*)&Adst[0] = h; *(f16x8*)&Adst[32] = l;
      split8(a2, a3, h, l);
      *(f16x8*)&Adst[8] = h; *(f16x8*)&Adst[40] = l;
    }
    if (Whi) {
      *(f16x8*)&Bdst[0] = wh0; *(f16x8*)&Bdst[32] = wl0;
      if (TN == 128) { *(f16x8*)&Bdst[8] = wh1; *(f16x8*)&Bdst[40] = wl1; }
    } else {
      f16x8 h, l;
      split8(b0, b1, h, l);
      *(f16x8*)&Bdst[0] = h; *(f16x8*)&Bdst[32] = l;
      if (TN == 128) {
        split8(b2, b3, h, l);
        *(f16x8*)&Bdst[8] = h; *(f16x8*)&Bdst[40] = l;
      }
    }
    __syncthreads();

    f16x8 bh[4], bl[4];
#pragma unroll
    for (int ni = 0; ni < 4; ni++) {
      bh[ni] = *(const f16x8*)&bb[ni * 16 * LSTR];
      bl[ni] = *(const f16x8*)&bb[ni * 16 * LSTR + 32];
    }
#pragma unroll
    for (int mi = 0; mi < MI; mi++) {
      f16x8 fah = *(const f16x8*)&ab[mi * 16 * LSTR];
      f16x8 fal = *(const f16x8*)&ab[mi * 16 * LSTR + 32];
#pragma unroll
      for (int ni = 0; ni < 4; ni++) {
        acc[mi][ni] = __builtin_amdgcn_mfma_f32_16x16x32_f16(fah, bh[ni], acc[mi][ni], 0, 0, 0);
        acc[mi][ni] = __builtin_amdgcn_mfma_f32_16x16x32_f16(fah, bl[ni], acc[mi][ni], 0, 0, 0);
        acc[mi][ni] = __builtin_amdgcn_mfma_f32_16x16x32_f16(fal, bh[ni], acc[mi][ni], 0, 0, 0);
      }
    }
  }

  float* dst = (S == 1) ? C : (P + (size_t)z * MM * N);
#pragma unroll
  for (int ni = 0; ni < 4; ni++) {
    const int n = n0 + w1 * 64 + ni * 16 + l16;
    const float bv = (S == 1 && bias) ? bias[n] : 0.f;
#pragma unroll
    for (int mi = 0; mi < MI; mi++) {
      const int mbase = m0 + rowbase + mi * 16 + quad * 4;
#pragma unroll
      for (int r = 0; r < 4; r++) {
        float v = acc[mi][ni][r] + bv;
        if (S == 1) {
          if (act == 1) v = fmaxf(v, 0.f);
          else if (act == 2) v = fmaxf(v, 0.f) + log1pf(__expf(-fabsf(v)));
        }
        dst[(size_t)(mbase + r) * N + n] = v;
      }
    }
  }
}

// ---------------------------------------------------------------------------
// Split-K reduce: C = act( sum_z P[z] + bias ).
// ---------------------------------------------------------------------------
__global__ __launch_bounds__(256) void reduce_k(
    const float* __restrict__ P, const float* __restrict__ bias,
    float* __restrict__ C, int nmask, int S, int act, int stride4)
{
  const int idx = blockIdx.x * 256 + threadIdx.x;
  float4 a = *(const float4*)&P[(size_t)idx * 4];
  for (int z = 1; z < S; z++) {
    float4 p = *(const float4*)&P[(size_t)(idx + z * (size_t)stride4) * 4];
    a.x += p.x; a.y += p.y; a.z += p.z; a.w += p.w;
  }
  if (bias) {
    float4 bv = *(const float4*)&bias[(idx * 4) & nmask];
    a.x += bv.x; a.y += bv.y; a.z += bv.z; a.w += bv.w;
  }
  if (act == 1) {
    a.x = fmaxf(a.x, 0.f); a.y = fmaxf(a.y, 0.f);
    a.z = fmaxf(a.z, 0.f); a.w = fmaxf(a.w, 0.f);
  } else if (act == 2) {
    a.x = fmaxf(a.x, 0.f) + log1pf(__expf(-fabsf(a.x)));
    a.y = fmaxf(a.y, 0.f) + log1pf(__expf(-fabsf(a.y)));
    a.z = fmaxf(a.z, 0.f) + log1pf(__expf(-fabsf(a.z)));
    a.w = fmaxf(a.w, 0.f) + log1pf(__expf(-fabsf(a.w)));
  }
  *(float4*)&C[(size_t)idx * 4] = a;
}

// ---------------------------------------------------------------------------
// MFMA flash attention (no-max softmax; scores bounded by construction).
// ---------------------------------------------------------------------------
__global__ __launch_bounds__(256) void attn_mfma_k(
    const float* __restrict__ qkv, float* __restrict__ o)
{
  __shared__ _Float16 Khi[AKS * 16], Klo[AKS * 16];
  __shared__ _Float16 Vthi[16 * VSTR], Vtlo[16 * VSTR];
  __shared__ float Pscr[4][16 * 18];

  const int tid = threadIdx.x;
  const int lane = tid & 63;
  const int wv = tid >> 6;
  const int quad = lane >> 4;
  const int l16 = lane & 15;
  const int qh = quad & 1;
  const int bh = blockIdx.y;
  const int b = bh >> 3;
  const int h = bh & 7;
  const int qb0 = blockIdx.x * 128;

  f16x8 qa[2];
#pragma unroll
  for (int u = 0; u < 2; u++) {
    const int qrow = qb0 + wv * 32 + u * 16 + l16;
    const float* qp = qkv + (size_t)(b * TT + qrow) * 384 + h * 16 + qh * 8;
    float4 x0 = *(const float4*)&qp[0];
    float4 x1 = *(const float4*)&qp[4];
    float xv[8] = {x0.x, x0.y, x0.z, x0.w, x1.x, x1.y, x1.z, x1.w};
#pragma unroll
    for (int j = 0; j < 8; j++) {
      float q = xv[j] * 0.25f;
      _Float16 hi = (_Float16)q;
      _Float16 lo = (_Float16)(q - (float)hi);
      qa[u][j] = (quad < 2) ? hi : lo;
    }
  }

  f32x4_t oacc[2];
  float lacc[2][4];
#pragma unroll
  for (int u = 0; u < 2; u++)
#pragma unroll
    for (int r = 0; r < 4; r++) { oacc[u][r] = 0.f; lacc[u][r] = 0.f; }

  float* Pw = &Pscr[wv][0];

  for (int ks = 0; ks < TT; ks += AKS) {
    __syncthreads();
    {
      const int key = tid >> 1, hf = tid & 1;
      const float* kp = qkv + (size_t)(b * TT + ks + key) * 384 + 128 + h * 16 + hf * 8;
      float4 k0 = *(const float4*)&kp[0];
      float4 k1 = *(const float4*)&kp[4];
      f16x8 vh, vl;
      split8(k0, k1, vh, vl);
      *(f16x8*)&Khi[key * 16 + hf * 8] = vh;
      *(f16x8*)&Klo[key * 16 + hf * 8] = vl;
      const float* vp = kp + 128;
      float4 v0 = *(const float4*)&vp[0];
      float4 v1 = *(const float4*)&vp[4];
      float vvv[8] = {v0.x, v0.y, v0.z, v0.w, v1.x, v1.y, v1.z, v1.w};
#pragma unroll
      for (int j = 0; j < 8; j++) {
        const int d = hf * 8 + j;
        _Float16 hi = (_Float16)vvv[j];
        Vthi[d * VSTR + key] = hi;
        Vtlo[d * VSTR + key] = (_Float16)(vvv[j] - (float)hi);
      }
    }
    __syncthreads();

    for (int kt = 0; kt < AKS; kt += 16) {
      f16x8 kfh = *(const f16x8*)&Khi[(kt + l16) * 16 + qh * 8];
      f16x8 kfl = *(const f16x8*)&Klo[(kt + l16) * 16 + qh * 8];
      const int vo = l16 * VSTR + kt + qh * 8;
      f16x4 va0 = *(const f16x4*)&Vthi[vo];
      f16x4 va1 = *(const f16x4*)&Vthi[vo + 4];
      f16x4 vb0 = *(const f16x4*)&Vtlo[vo];
      f16x4 vb1 = *(const f16x4*)&Vtlo[vo + 4];
      f16x8 vfh, vfl;
#pragma unroll
      for (int i = 0; i < 4; i++) {
        vfh[i] = va0[i]; vfh[4 + i] = va1[i];
        vfl[i] = vb0[i]; vfl[4 + i] = vb1[i];
      }

#pragma unroll
      for (int u = 0; u < 2; u++) {
        f32x4_t s;
#pragma unroll
        for (int r = 0; r < 4; r++) s[r] = 0.f;
        s = __builtin_amdgcn_mfma_f32_16x16x32_f16(qa[u], kfh, s, 0, 0, 0);
        s = __builtin_amdgcn_mfma_f32_16x16x32_f16(qa[u], kfl, s, 0, 0, 0);
        float p[4];
#pragma unroll
        for (int r = 0; r < 4; r++) {
          p[r] = __expf(s[r]);
          lacc[u][r] += p[r];
        }
        float* ps = Pw + (quad * 4) * 18 + l16;
        ps[0] = p[0]; ps[18] = p[1]; ps[36] = p[2]; ps[54] = p[3];
        __asm__ volatile("s_waitcnt lgkmcnt(0)" ::: "memory");
        const float* pr = Pw + l16 * 18 + qh * 8;
        f16x8 pa;
#pragma unroll
        for (int j = 0; j < 8; j++) {
          float pv = pr[j];
          _Float16 hi = (_Float16)pv;
          _Float16 lo = (_Float16)(pv - (float)hi);
          pa[j] = (quad < 2) ? hi : lo;
        }
        oacc[u] = __builtin_amdgcn_mfma_f32_16x16x32_f16(pa, vfh, oacc[u], 0, 0, 0);
        oacc[u] = __builtin_amdgcn_mfma_f32_16x16x32_f16(pa, vfl, oacc[u], 0, 0, 0);
        __asm__ volatile("s_waitcnt lgkmcnt(0)" ::: "memory");
      }
    }
  }

#pragma unroll
  for (int u = 0; u < 2; u++) {
#pragma unroll
    for (int r = 0; r < 4; r++) {
      float lv = lacc[u][r];
      lv += __shfl_xor(lv, 1);
      lv += __shfl_xor(lv, 2);
      lv += __shfl_xor(lv, 4);
      lv += __shfl_xor(lv, 8);
      const float inv = 1.f / lv;
      const int qrow = qb0 + wv * 32 + u * 16 + quad * 4 + r;
      o[(size_t)(b * TT + qrow) * 128 + h * 16 + l16] = oacc[u][r] * inv;
    }
  }
}

// ---------------------------------------------------------------------------
// out = LN(a + bvec) * w + bb
// ---------------------------------------------------------------------------
__global__ __launch_bounds__(256) void add_ln_k(
    const float* __restrict__ a, const float* __restrict__ bvec,
    const float* __restrict__ w, const float* __restrict__ bb,
    float* __restrict__ out)
{
  const int tid = threadIdx.x;
  const int wave = tid >> 6, lane = tid & 63;
  const size_t row = (size_t)blockIdx.x * 4 + wave;
  const float* pa = a + row * 128;
  const float* pb = bvec + row * 128;
  float v0 = pa[lane] + pb[lane];
  float v1 = pa[lane + 64] + pb[lane + 64];
  float s1 = v0 + v1, s2 = v0 * v0 + v1 * v1;
#pragma unroll
  for (int off = 32; off; off >>= 1) {
    s1 += __shfl_down(s1, off);
    s2 += __shfl_down(s2, off);
  }
  s1 = __shfl(s1, 0); s2 = __shfl(s2, 0);
  const float mean = s1 * (1.f / 128.f);
  const float var = s2 * (1.f / 128.f) - mean * mean;
  const float rs = rsqrtf(var + EPSV);
  out[row * 128 + lane]      = (v0 - mean) * rs * w[lane] + bb[lane];
  out[row * 128 + lane + 64] = (v1 - mean) * rs * w[lane + 64] + bb[lane + 64];
}

// ---------------------------------------------------------------------------
// Depthwise causal conv (DC=4) + SiLU
// ---------------------------------------------------------------------------
__global__ __launch_bounds__(256) void conv_silu_k(
    const float* __restrict__ xz, const float* __restrict__ cw,
    const float* __restrict__ cb, float* __restrict__ out)
{
  const int idx = blockIdx.x * 256 + threadIdx.x;
  const int di = idx & 1023;
  const int m = idx >> 10;
  const int t = m & (TT - 1);
  float acc = cb[di];
#pragma unroll
  for (int k = 0; k < 4; k++) {
    int tt = t + k - 3;
    if (tt >= 0) acc += xz[(size_t)(m + k - 3) * 2048 + di] * cw[di * 4 + k];
  }
  out[(size_t)m * 1024 + di] = acc / (1.f + __expf(-acc));
}

// ---------------------------------------------------------------------------
// Chunked selective scan, phase A.
// ---------------------------------------------------------------------------
__global__ __launch_bounds__(64) void scan_partial_k(
    const float* __restrict__ dt,
    const float* __restrict__ dbc,
    const float* __restrict__ xi,
    const float* __restrict__ Alog,
    float* __restrict__ Pb, float* __restrict__ Sb)
{
  const int slice = blockIdx.x & 15;
  const int c = blockIdx.x >> 4;
  const int b = blockIdx.y;
  const int di = slice * 64 + threadIdx.x;

  float A[NSTATE];
#pragma unroll
  for (int n = 0; n < NSTATE; n++) A[n] = -__expf(Alog[di * NSTATE + n]);
  float h[NSTATE], P[NSTATE];
#pragma unroll
  for (int n = 0; n < NSTATE; n++) { h[n] = 0.f; P[n] = 1.f; }

  const size_t m0 = (size_t)b * TT + (size_t)c * CHUNK;
  for (int t = 0; t < CHUNK; t++) {
    const size_t m = m0 + t;
    const float dtv = dt[m * 1024 + di];
    const float xv  = xi[m * 1024 + di];
    const float dtx = dtv * xv;
#pragma unroll
    for (int n = 0; n < NSTATE; n++) {
      const float Bv = dbc[m * 64 + 32 + n];
      const float dA = __expf(dtv * A[n]);
      h[n] = h[n] * dA + dtx * Bv;
      P[n] *= dA;
    }
  }
  const size_t base = (((size_t)b * NCH + c) * NSTATE) * 1024 + di;
#pragma unroll
  for (int n = 0; n < NSTATE; n++) {
    Pb[base + (size_t)n * 1024] = P[n];
    Sb[base + (size_t)n * 1024] = h[n];
  }
}

// ---------------------------------------------------------------------------
// Phase B: sequential chunk fix-up per (b, di).
// ---------------------------------------------------------------------------
__global__ __launch_bounds__(256) void scan_fix_k(
    float* __restrict__ Pb, const float* __restrict__ Sb)
{
  const int idx = blockIdx.x * 256 + threadIdx.x;
  const int b = idx >> 10;
  const int di = idx & 1023;
  float h[NSTATE];
#pragma unroll
  for (int n = 0; n < NSTATE; n++) h[n] = 0.f;
  for (int c = 0; c < NCH; c++) {
    const size_t base = (((size_t)b * NCH + c) * NSTATE) * 1024 + di;
    float P[NSTATE], S[NSTATE];
#pragma unroll
    for (int n = 0; n < NSTATE; n++) {
      P[n] = Pb[base + (size_t)n * 1024];
      S[n] = Sb[base + (size_t)n * 1024];
    }
#pragma unroll
    for (int n = 0; n < NSTATE; n++) {
      Pb[base + (size_t)n * 1024] = h[n];
      h[n] = P[n] * h[n] + S[n];
    }
  }
}

// ---------------------------------------------------------------------------
// Phase C: re-run each chunk from h_in; y = dot(h,C) + D*x; *= silu(z).
// ---------------------------------------------------------------------------
__global__ __launch_bounds__(64) void scan_final_k(
    const float* __restrict__ dt,
    const float* __restrict__ dbc,
    const float* __restrict__ xi,
    const float* __restrict__ xz,
    const float* __restrict__ Alog,
    const float* __restrict__ Dp,
    const float* __restrict__ Hin,
    float* __restrict__ Y)
{
  const int slice = blockIdx.x & 15;
  const int c = blockIdx.x >> 4;
  const int b = blockIdx.y;
  const int di = slice * 64 + threadIdx.x;

  float A[NSTATE];
#pragma unroll
  for (int n = 0; n < NSTATE; n++) A[n] = -__expf(Alog[di * NSTATE + n]);
  const float Dv = Dp[di];
  float h[NSTATE];
  const size_t hbase = (((size_t)b * NCH + c) * NSTATE) * 1024 + di;
#pragma unroll
  for (int n = 0; n < NSTATE; n++) h[n] = Hin[hbase + (size_t)n * 1024];

  const size_t m0 = (size_t)b * TT + (size_t)c * CHUNK;
  for (int t = 0; t < CHUNK; t++) {
    const size_t m = m0 + t;
    const float dtv = dt[m * 1024 + di];
    const float xv  = xi[m * 1024 + di];
    const float zv  = xz[m * 2048 + 1024 + di];
    const float dtx = dtv * xv;
    float y = 0.f;
#pragma unroll
    for (int n = 0; n < NSTATE; n++) {
      const float Bv = dbc[m * 64 + 32 + n];
      const float Cv = dbc[m * 64 + 48 + n];
      const float dA = __expf(dtv * A[n]);
      h[n] = h[n] * dA + dtx * Bv;
      y += h[n] * Cv;
    }
    y += Dv * xv;
    y *= zv / (1.f + __expf(-zv));
    Y[m * 1024 + di] = y;
  }
}

// ---------------------------------------------------------------------------
extern "C" void kernel_launch(void* const* d_in, const int* in_sizes, int n_in,
                              void* d_out, int out_size, void* d_ws, size_t ws_size,
                              hipStream_t stream)
{
  const float* emb      = (const float*)d_in[0];
  const float* t_wqkv   = (const float*)d_in[1];
  const float* t_bqkv   = (const float*)d_in[2];
  const float* t_wo     = (const float*)d_in[3];
  const float* t_bo     = (const float*)d_in[4];
  const float* t_ln1w   = (const float*)d_in[5];
  const float* t_ln1b   = (const float*)d_in[6];
  const float* t_w1     = (const float*)d_in[7];
  const float* t_b1     = (const float*)d_in[8];
  const float* t_w2     = (const float*)d_in[9];
  const float* t_b2     = (const float*)d_in[10];
  const float* t_ln2w   = (const float*)d_in[11];
  const float* t_ln2b   = (const float*)d_in[12];
  const float* w_in     = (const float*)d_in[13];
  const float* b_in     = (const float*)d_in[14];
  const float* m_inproj = (const float*)d_in[15];
  const float* m_convw  = (const float*)d_in[16];
  const float* m_convb  = (const float*)d_in[17];
  const float* m_xproj  = (const float*)d_in[18];
  const float* m_dtw    = (const float*)d_in[19];
  const float* m_dtb    = (const float*)d_in[20];
  const float* m_Alog   = (const float*)d_in[21];
  const float* m_D      = (const float*)d_in[22];
  const float* m_outproj= (const float*)d_in[23];
  const float* w_out    = (const float*)d_in[24];
  const float* b_out    = (const float*)d_in[25];

  float* ws = (float*)d_ws;
  float* X0   = ws;                               // M*512
  float* X1   = X0 + (size_t)MM * 512;            // M*512
  float* Abuf = X1 + (size_t)MM * 512;            // M*2048
  float* Bf   = Abuf + (size_t)MM * 2048;         // M*1024
  float* Cf   = Bf + (size_t)MM * 1024;           // M*1024
  float* Yb   = Cf + (size_t)MM * 1024;           // M*1024
  float* Db   = Yb + (size_t)MM * 1024;           // M*64

  // weight pre-split arena (hi plane then lo plane per tensor)
  const size_t baseFloats = (size_t)MM * 6208;
  const size_t wqE = (size_t)NTT * 384 * 128;     // 294912
  const size_t woE = (size_t)NTT * 128 * 128;     // 98304
  const size_t w1E = (size_t)NTT * 2048 * 128;    // 1572864
  const size_t w2E = (size_t)NTT * 128 * 2048;    // 1572864
  const size_t wiE = (size_t)512 * 128;           // 65536
  const size_t ipE = (size_t)NMM * 2048 * 512;    // 8388608
  const size_t xpE = (size_t)NMM * 64 * 1024;     // 524288
  const size_t dwE = (size_t)NMM * 1024 * 32;     // 262144
  const size_t opE = (size_t)NMM * 512 * 1024;    // 4194304
  const size_t woutE = (size_t)128 * 512;         // 65536
  const size_t totalWE = wqE + woE + w1E + w2E + wiE + ipE + xpE + dwE + opE + woutE;
  const bool pre = ws_size >= baseFloats * 4 + totalWE * 4;
  _Float16* Wa = (_Float16*)(ws + baseFloats);
  size_t off = 0;
  auto plane = [&](size_t cnt) { _Float16* p = Wa + off; off += 2 * cnt; return p; };
  _Float16* wqP = plane(wqE); _Float16* woP = plane(woE);
  _Float16* w1P = plane(w1E); _Float16* w2P = plane(w2E);
  _Float16* wiP = plane(wiE); _Float16* ipP = plane(ipE);
  _Float16* xpP = plane(xpE); _Float16* dwP = plane(dwE);
  _Float16* opP = plane(opE); _Float16* woutP = plane(woutE);

  dim3 blk(256);
  auto dosplit = [&](const float* src, _Float16* hi, size_t cnt) {
    hipLaunchKernelGGL(split_k, dim3((unsigned)(cnt / 1024)), blk, 0, stream,
                       src, hi, hi + cnt);
  };
  if (pre) {
    dosplit(t_wqkv, wqP, wqE);   dosplit(t_wo, woP, woE);
    dosplit(t_w1, w1P, w1E);     dosplit(t_w2, w2P, w2E);
    dosplit(w_in, wiP, wiE);     dosplit(m_inproj, ipP, ipE);
    dosplit(m_xproj, xpP, xpE);  dosplit(m_dtw, dwP, dwE);
    dosplit(m_outproj, opP, opE); dosplit(w_out, woutP, woutE);
  }

  auto gemm = [&](const float* A, int lda, const float* W, const float* bias,
                  float* C, int N, int K, int act, int S, float* P, bool tn64,
                  const _Float16* Ahi, const _Float16* Whi, size_t wcnt) {
    dim3 g(N / (tn64 ? 64 : 128), MM / 128, S);
    const _Float16* Alo = Ahi ? Ahi + (size_t)MM * K : nullptr;
    const _Float16* Wlo = (pre && Whi) ? Whi + wcnt : nullptr;
    const _Float16* Whi2 = pre ? Whi : nullptr;
    if (tn64)
      hipLaunchKernelGGL(gemm_mfma_t<64>, g, blk, 0, stream,
                         A, lda, W, Ahi, Alo, Whi2, Wlo,
                         S == 1 ? bias : nullptr, C, P, N, K, S, act);
    else
      hipLaunchKernelGGL(gemm_mfma_t<128>, g, blk, 0, stream,
                         A, lda, W, Ahi, Alo, Whi2, Wlo,
                         S == 1 ? bias : nullptr, C, P, N, K, S, act);
    if (S > 1) {
      int stride4 = (MM * N) / 4;
      hipLaunchKernelGGL(reduce_k, dim3(stride4 / 256), blk, 0, stream,
                         P, bias, C, N - 1, S, act, stride4);
    }
  };

  const float* x = emb;
  for (int l = 0; l < NTT; l++) {
    // qkv: A-planes into Cf (dead), N=384 K=128
    _Float16* aP = (_Float16*)Cf;
    hipLaunchKernelGGL(split_k, dim3(MM * 128 / 1024), blk, 0, stream,
                       x, aP, aP + (size_t)MM * 128);
    gemm(x, 128, t_wqkv + (size_t)l * 384 * 128, t_bqkv + l * 384,
         Abuf, 384, 128, 0, 1, nullptr, false,
         aP, wqP + (size_t)l * 384 * 128, wqE);
    hipLaunchKernelGGL(attn_mfma_k, dim3(TT / 128, HB * 8), blk, 0, stream,
                       Abuf, Yb);
    // wo: N=128 K=128 -> TN64, S=2, partials in X1
    gemm(Yb, 128, t_wo + (size_t)l * 128 * 128, t_bo + l * 128,
         Cf, 128, 128, 0, 2, X1, true,
         nullptr, woP + (size_t)l * 128 * 128, woE);
    hipLaunchKernelGGL(add_ln_k, dim3(MM / 4), blk, 0, stream,
                       x, Cf, t_ln1w + l * 128, t_ln1b + l * 128, X0);
    // w1: A-planes into Yb (dead after wo), N=2048 K=128
    aP = (_Float16*)Yb;
    hipLaunchKernelGGL(split_k, dim3(MM * 128 / 1024), blk, 0, stream,
                       X0, aP, aP + (size_t)MM * 128);
    gemm(X0, 128, t_w1 + (size_t)l * 2048 * 128, t_b1 + l * 2048,
         Abuf, 2048, 128, 1, 1, nullptr, false,
         aP, w1P + (size_t)l * 2048 * 128, w1E);
    // w2: N=128 K=2048 -> S=8, partials in Yb
    gemm(Abuf, 2048, t_w2 + (size_t)l * 128 * 2048, t_b2 + l * 128,
         Cf, 128, 2048, 0, 8, Yb, false,
         nullptr, w2P + (size_t)l * 128 * 2048, w2E);
    hipLaunchKernelGGL(add_ln_k, dim3(MM / 4), blk, 0, stream,
                       X0, Cf, t_ln2w + l * 128, t_ln2b + l * 128, X0);
    x = X0;
  }

  // w_in: A-planes into Cf (dead), N=512 K=128
  {
    _Float16* aP = (_Float16*)Cf;
    hipLaunchKernelGGL(split_k, dim3(MM * 128 / 1024), blk, 0, stream,
                       X0, aP, aP + (size_t)MM * 128);
    gemm(X0, 128, w_in, b_in, X1, 512, 128, 0, 1, nullptr, false,
         aP, wiP, wiE);
  }

  float* xc = X1;
  float* xo = X0;
  for (int l = 0; l < NMM; l++) {
    // inproj: A-planes into Cf (dead: prev dt consumed), N=2048 K=512
    _Float16* aP = (_Float16*)Cf;
    hipLaunchKernelGGL(split_k, dim3(MM * 512 / 1024), blk, 0, stream,
                       xc, aP, aP + (size_t)MM * 512);
    gemm(xc, 512, m_inproj + (size_t)l * 2048 * 512, nullptr,
         Abuf, 2048, 512, 0, 1, nullptr, false,
         aP, ipP + (size_t)l * 2048 * 512, ipE);
    hipLaunchKernelGGL(conv_silu_k, dim3(MM * 1024 / 256), blk, 0, stream,
                       Abuf, m_convw + (size_t)l * 1024 * 4, m_convb + l * 1024, Bf);
    // xproj: N=64 K=1024 -> TN64, S=4, partials in xo
    gemm(Bf, 1024, m_xproj + (size_t)l * 64 * 1024, nullptr,
         Db, 64, 1024, 0, 4, xo, true,
         nullptr, xpP + (size_t)l * 64 * 1024, xpE);
    // dtw: N=1024 K=32, softplus
    gemm(Db, 64, m_dtw + (size_t)l * 1024 * 32, m_dtb + l * 1024,
         Cf, 1024, 32, 2, 1, nullptr, false,
         nullptr, dwP + (size_t)l * 1024 * 32, dwE);

    float* Pb = xo;
    float* Sb = xo + (size_t)HB * NCH * NSTATE * 1024;
    hipLaunchKernelGGL(scan_partial_k, dim3(16 * NCH, HB), dim3(64), 0, stream,
                       Cf, Db, Bf, m_Alog + (size_t)l * 1024 * 16, Pb, Sb);
    hipLaunchKernelGGL(scan_fix_k, dim3(MM / 1024 * 4), blk, 0, stream, Pb, Sb);
    hipLaunchKernelGGL(scan_final_k, dim3(16 * NCH, HB), dim3(64), 0, stream,
                       Cf, Db, Bf, Abuf,
                       m_Alog + (size_t)l * 1024 * 16, m_D + l * 1024, Pb, Yb);

    // outproj: N=512 K=1024 -> S=2, partials in Abuf
    gemm(Yb, 1024, m_outproj + (size_t)l * 512 * 1024, nullptr,
         xo, 512, 1024, 0, 2, Abuf, false,
         nullptr, opP + (size_t)l * 512 * 1024, opE);
    float* tmp = xc; xc = xo; xo = tmp;
  }

  // w_out: N=128 K=512 -> S=4, partials in Yb
  gemm(xc, 512, w_out, b_out, (float*)d_out, 128, 512, 0, 4, Yb, false,
       nullptr, woutP, woutE);
}